// Round 18
// baseline (139.111 us; speedup 1.0000x reference)
//
#include <hip/hip_runtime.h>
#include <math.h>

// Problem constants
#define NB 4
#define NC 2048
#define NH 8
#define NK 128
#define NG 255          // a-grid points per (b,h)

// exp2-domain logit scale: log2(e)/sqrt(128)
#define A2SCALE (1.4426950408889634f * 0.08838834764831845f)

typedef __attribute__((ext_vector_type(8))) short bf16x8;
typedef __attribute__((ext_vector_type(4))) float f32x4;

// ---------------- ws layout (float offsets) ----------------
// wspart [4][2048]           @ 0        (8192)
// W2     [8][128][128]       @ 8192     (131072)  dead after prep2 ->
//   mm   [32][2]             @ 8192     amin,hstep per bh
// qs     [32][2048]          @ 139264
// ks     [32][2048]          @ 204800
// u bf16 [32][64ig][8nt][64lane][8j] @ 270336 (8,388,608 ushort)
// partsN [32][4sl][255][128] @ 4464640  (4,177,920) -> slice0 becomes tablef
// cnt    [128] uint          @ 8642560  (bh,gt) completion counters
// parts_z [32][4][255] lives in d_out (overwritten by k_eval)
#define OFF_W2   8192
#define OFF_MM   8192
#define OFF_QS   139264
#define OFF_KS   204800
#define OFF_U    270336
#define OFF_PN   4464640
#define OFF_CNT  8642560

__device__ static inline float exp2_hw(float x) {
#if __has_builtin(__builtin_amdgcn_exp2f)
    return __builtin_amdgcn_exp2f(x);
#else
    float r;
    asm volatile("v_exp_f32 %0, %1\n\ts_nop 1" : "=v"(r) : "v"(x));
    return r;
#endif
}

__device__ static inline unsigned cvtpk(float lo, float hi) {
    unsigned r;
    asm("v_cvt_pk_bf16_f32 %0, %1, %2" : "=v"(r) : "v"(lo), "v"(hi));
    return r;
}

__device__ static inline bf16x8 pack8(float4 a, float4 b) {
    union { unsigned u[4]; bf16x8 v; } r;
    r.u[0] = cvtpk(a.x, a.y);
    r.u[1] = cvtpk(a.z, a.w);
    r.u[2] = cvtpk(b.x, b.y);
    r.u[3] = cvtpk(b.z, b.w);
    return r.v;
}

// 8 exps of (a*k + negM) packed to a bf16x8 A-fragment; accumulates sum in z
__device__ static inline bf16x8 pexp8s(float4 ka, float4 kb, float a, float negM,
                                       float& z) {
    float e0 = exp2_hw(fmaf(a, ka.x, negM));
    float e1 = exp2_hw(fmaf(a, ka.y, negM));
    float e2 = exp2_hw(fmaf(a, ka.z, negM));
    float e3 = exp2_hw(fmaf(a, ka.w, negM));
    float e4 = exp2_hw(fmaf(a, kb.x, negM));
    float e5 = exp2_hw(fmaf(a, kb.y, negM));
    float e6 = exp2_hw(fmaf(a, kb.z, negM));
    float e7 = exp2_hw(fmaf(a, kb.w, negM));
    z += ((e0 + e1) + (e2 + e3)) + ((e4 + e5) + (e6 + e7));
    union { unsigned u[4]; bf16x8 v; } r;
    r.u[0] = cvtpk(e0, e1);
    r.u[1] = cvtpk(e2, e3);
    r.u[2] = cvtpk(e4, e5);
    r.u[3] = cvtpk(e6, e7);
    return r.v;
}

// ---- prep1: (blk<64) wsum + cnt init ; (blk>=64) W2 ----  grid 576 x 256
// (R13 body + counter zeroing)
__global__ __launch_bounds__(256) void k_prep1(const float* __restrict__ Wq,
                                               const float* __restrict__ Wk,
                                               const float* __restrict__ Wv,
                                               const float* __restrict__ Wo,
                                               float* __restrict__ wspart,
                                               float* __restrict__ W2,
                                               unsigned* __restrict__ cnt) {
    int blk = blockIdx.x;
    int tid = threadIdx.x;
    __shared__ float sh[256];
    if (blk < 64) {
        int which = blk >> 5, h = (blk >> 2) & 7, eq = blk & 3;
        const float* W = which ? Wk : Wq;
        int m = tid & 127, part = tid >> 7;
        const float* base = W + (h * 128 + eq * 32 + part * 16) * 128 + m;
        float s = 0.f;
#pragma unroll
        for (int e = 0; e < 16; ++e) s += base[e * 128];
        if (part) sh[m] = s;
        __syncthreads();
        if (!part) wspart[eq * 2048 + which * 1024 + h * 128 + m] = s + sh[m];
        if (blk == 0 && tid < 128) cnt[tid] = 0u;   // (bh,gt) counters
    } else {
        int idx = blk - 64;                    // 0..511
        int h = idx >> 6;
        int kl = tid >> 7;                     // 0..1
        int kk = (idx & 63) * 2 + kl;
        int m = tid & 127;
        float* wo_s = sh;                      // [2][128]
        wo_s[kl * 128 + m] = Wo[kk * 1024 + h * 128 + m];
        __syncthreads();
        const float* base = Wv + (h * 128) * 128 + m;
        const float* wrow = &wo_s[kl * 128];
        float s = 0.f;
#pragma unroll 4
        for (int e = 0; e < 128; ++e) s += base[e * 128] * wrow[e];
        W2[(h * 128 + kk) * 128 + m] = s;
    }
}

// ---- prep2: (blk<256) qs/ks ; (blk>=256) u-GEMM ----  grid 768 x 256
// (R13-identical)
__global__ __launch_bounds__(256) void k_prep2(const float* __restrict__ x,
                                               const float* __restrict__ wspart,
                                               const float* __restrict__ W2,
                                               float* __restrict__ qs,
                                               float* __restrict__ ks,
                                               unsigned short* __restrict__ u16) {
    __shared__ __align__(16) unsigned char smem_u8[32768];
    int tid = threadIdx.x;
    int blk = blockIdx.x;
    if (blk < 256) {
        float* xs = (float*)smem_u8;              // [32][129]
        float* wsum = (float*)smem_u8 + 32 * 129; // [2048]
        for (int j = tid; j < 2048; j += 256)
            wsum[j] = wspart[j] + wspart[2048 + j] + wspart[4096 + j] + wspart[6144 + j];
        int row0 = blk * 32;
        for (int j = tid; j < 32 * 128; j += 256) {
            int r = j >> 7, m = j & 127;
            xs[r * 129 + m] = x[(size_t)(row0 + r) * 128 + m];
        }
        __syncthreads();
#pragma unroll
        for (int jj = 0; jj < 2; ++jj) {
            int o = tid + 256 * jj;
            int r = o & 31;
            int q = o >> 5;
            int which = q >> 3, h = q & 7;
            const float* wrow = &wsum[which * 1024 + h * 128];
            const float* xrow = &xs[r * 129];
            float s = 0.f;
#pragma unroll 4
            for (int m = 0; m < 128; ++m) s += xrow[m] * wrow[m];
            int row = row0 + r, b = row >> 11, t = row & 2047;
            float* dst = which ? ks : qs;
            dst[(b * 8 + h) * 2048 + t] = s;
        }
    } else {
        int gid = blk - 256;
        int xcd = gid & 7, s = gid >> 3;
        int bh = xcd * 4 + (s >> 4);
        int it = s & 15;
        int b = bh >> 3, h = bh & 7;
        int lane = tid & 63, wid = tid >> 6;
        int wr = wid >> 1, wc = wid & 1;
        int l15 = lane & 15, l4 = lane >> 4;

        const float* xb = x + (size_t)(b * 2048 + it * 128) * 128;
        const float* w2h = W2 + h * 16384;

        f32x4 acc[4][4];
#pragma unroll
        for (int m = 0; m < 4; ++m)
#pragma unroll
            for (int n = 0; n < 4; ++n) acc[m][n] = (f32x4)0.f;

#pragma unroll
        for (int mg = 0; mg < 4; ++mg) {
            bf16x8 af[4], bfr[4];
#pragma unroll
            for (int m = 0; m < 4; ++m) {
                const float* src = xb + (wr * 64 + m * 16 + l15) * 128 + mg * 32 + l4 * 8;
                af[m] = pack8(*(const float4*)src, *(const float4*)(src + 4));
            }
#pragma unroll
            for (int n = 0; n < 4; ++n) {
                const float* src = w2h + (wc * 64 + n * 16 + l15) * 128 + mg * 32 + l4 * 8;
                bfr[n] = pack8(*(const float4*)src, *(const float4*)(src + 4));
            }
#pragma unroll
            for (int m = 0; m < 4; ++m)
#pragma unroll
                for (int n = 0; n < 4; ++n)
                    acc[m][n] = __builtin_amdgcn_mfma_f32_16x16x32_bf16(
                        af[m], bfr[n], acc[m][n], 0, 0, 0);
        }

        unsigned* u_sh = (unsigned*)smem_u8;
#pragma unroll
        for (int m = 0; m < 4; ++m) {
            int i_base = wr * 64 + m * 16 + l4 * 4;
            int ig = i_base >> 5;
            int lg = 16 * ((i_base >> 3) & 3);
            int jp = (i_base & 7) >> 1;
#pragma unroll
            for (int n = 0; n < 4; ++n) {
                int kk = wc * 64 + n * 16 + l15;
                int lp = (kk & 15) + lg;
                int idx = ((ig * 8 + (kk >> 4)) * 64 + lp) * 4 + jp;
                uint2 w;
                w.x = cvtpk(acc[m][n][0], acc[m][n][1]);
                w.y = cvtpk(acc[m][n][2], acc[m][n][3]);
                *(uint2*)&u_sh[idx] = w;
            }
        }
        __syncthreads();
        unsigned short* ub = u16 + ((size_t)(b * 8 + h) * 64 + it * 4) * 4096;
#pragma unroll
        for (int q = 0; q < 8; ++q)
            ((uint4*)ub)[tid + q * 256] = ((const uint4*)u_sh)[tid + q * 256];
    }
}

// ---- k_table: tabulate N_g, z_g; last block per (bh,gt) reduces in place ----
// grid 512 x 256 (R13 convoy verbatim + fence/counter/last-block-reduce)
__global__ __launch_bounds__(256, 2) void k_table(const float* __restrict__ qs,
                                                  const float* __restrict__ ks,
                                                  const unsigned short* __restrict__ ub,
                                                  float* __restrict__ pN,
                                                  float* __restrict__ pz,
                                                  float* __restrict__ mm,
                                                  unsigned* __restrict__ cnt) {
    int L = blockIdx.x;
    int xcd = L & 7, s = L >> 3;
    int bh = xcd * 4 + (s >> 4);
    int rem = s & 15;
    int gt = rem >> 2, sl = rem & 3;
    int tid = threadIdx.x;
    int lane = tid & 63, wid = tid >> 6;
    int l15 = lane & 15, l4 = lane >> 4;

    __shared__ float kss[2048];
    __shared__ __align__(16) unsigned short u_l[3][4096];
    __shared__ float red[8];
    __shared__ unsigned oldc;

    // ---- phase 1: qs min/max -> amin, hstep ----
    for (int j = tid; j < 512; j += 256)
        ((float4*)kss)[j] = ((const float4*)(qs + bh * 2048))[j];
    __syncthreads();
    float mn = 1e30f, mx = -1e30f;
    {
        const float4* ka = (const float4*)kss;
#pragma unroll
        for (int jj = 0; jj < 2; ++jj) {
            float4 v = ka[tid + jj * 256];
            mn = fminf(mn, fminf(fminf(v.x, v.y), fminf(v.z, v.w)));
            mx = fmaxf(mx, fmaxf(fmaxf(v.x, v.y), fmaxf(v.z, v.w)));
        }
#pragma unroll
        for (int off = 32; off; off >>= 1) {
            mn = fminf(mn, __shfl_xor(mn, off));
            mx = fmaxf(mx, __shfl_xor(mx, off));
        }
        if (!lane) { red[wid] = mn; red[4 + wid] = mx; }
    }
    __syncthreads();
    mn = fminf(fminf(red[0], red[1]), fminf(red[2], red[3]));
    mx = fmaxf(fmaxf(red[4], red[5]), fmaxf(red[6], red[7]));
    float amin = mn * A2SCALE;
    float hstep = fmaxf((mx * A2SCALE - amin), 1e-6f) * (1.f / (NG - 1));
    if (tid == 0) { mm[bh * 2] = amin; mm[bh * 2 + 1] = hstep; }
    __syncthreads();

    // ---- phase 2: ks stage + global min/max ----
    for (int j = tid; j < 512; j += 256)
        ((float4*)kss)[j] = ((const float4*)(ks + bh * 2048))[j];
    __syncthreads();
    mn = 1e30f; mx = -1e30f;
    {
        const float4* ka = (const float4*)kss;
#pragma unroll
        for (int jj = 0; jj < 2; ++jj) {
            float4 v = ka[tid + jj * 256];
            mn = fminf(mn, fminf(fminf(v.x, v.y), fminf(v.z, v.w)));
            mx = fmaxf(mx, fmaxf(fmaxf(v.x, v.y), fmaxf(v.z, v.w)));
        }
#pragma unroll
        for (int off = 32; off; off >>= 1) {
            mn = fminf(mn, __shfl_xor(mn, off));
            mx = fmaxf(mx, __shfl_xor(mx, off));
        }
        if (!lane) { red[wid] = mn; red[4 + wid] = mx; }
    }
    __syncthreads();
    mn = fminf(fminf(red[0], red[1]), fminf(red[2], red[3]));
    mx = fmaxf(fmaxf(red[4], red[5]), fmaxf(red[6], red[7]));

    int grow = gt * 64 + wid * 16 + l15;
    float a = fmaf((float)grow, hstep, amin);
    float negM = -(a > 0.f ? a * mx : a * mn);   // exact max over ALL i
    float zacc = 0.f;

    const unsigned short* gub = ub + (size_t)bh * 262144 + (size_t)sl * 65536;

    f32x4 acc[8];
#pragma unroll
    for (int n = 0; n < 8; ++n) acc[n] = (f32x4)0.f;

#define DMA(cnv, buf) do {                                                     \
    const unsigned short* src_ = gub + (size_t)(cnv) * 4096;                   \
    _Pragma("unroll")                                                          \
    for (int q_ = 0; q_ < 2; ++q_) {                                           \
        int seg_ = q_ * 4 + wid;                                               \
        __builtin_amdgcn_global_load_lds(                                      \
            (const __attribute__((address_space(1))) unsigned int*)(src_ + seg_ * 512 + lane * 8), \
            (__attribute__((address_space(3))) unsigned int*)(&u_l[buf][seg_ * 512]),              \
            16, 0, 0);                                                         \
    }                                                                          \
} while (0)

    DMA(0, 0);
    DMA(1, 1);
    for (int cn = 0; cn < 15; ++cn) {
        int cur = cn % 3;
        int ib = sl * 512 + cn * 32;
        float4 ka = *(const float4*)&kss[ib + l4 * 8];
        float4 kb = *(const float4*)&kss[ib + l4 * 8 + 4];
        bf16x8 pf = pexp8s(ka, kb, a, negM, zacc);

        asm volatile("s_waitcnt vmcnt(2)" ::: "memory");
        __builtin_amdgcn_sched_barrier(0);
        __builtin_amdgcn_s_barrier();
        __builtin_amdgcn_sched_barrier(0);
        if (cn + 2 <= 15) DMA(cn + 2, (cn + 2) % 3);
        __builtin_amdgcn_sched_barrier(0);

        __builtin_amdgcn_s_setprio(1);
#pragma unroll
        for (int n = 0; n < 8; ++n) {
            bf16x8 uf = *(const bf16x8*)&u_l[cur][n * 512 + lane * 8];
            acc[n] = __builtin_amdgcn_mfma_f32_16x16x32_bf16(pf, uf, acc[n], 0, 0, 0);
        }
        __builtin_amdgcn_s_setprio(0);
    }
    {   // tail: chunk 15 (buf 15%3 == 0)
        int ib = sl * 512 + 15 * 32;
        float4 ka = *(const float4*)&kss[ib + l4 * 8];
        float4 kb = *(const float4*)&kss[ib + l4 * 8 + 4];
        bf16x8 pf = pexp8s(ka, kb, a, negM, zacc);
        asm volatile("s_waitcnt vmcnt(0)" ::: "memory");
        __builtin_amdgcn_sched_barrier(0);
        __builtin_amdgcn_s_barrier();
        __builtin_amdgcn_sched_barrier(0);
#pragma unroll
        for (int n = 0; n < 8; ++n) {
            bf16x8 uf = *(const bf16x8*)&u_l[0][n * 512 + lane * 8];
            acc[n] = __builtin_amdgcn_mfma_f32_16x16x32_bf16(pf, uf, acc[n], 0, 0, 0);
        }
    }
#undef DMA

    zacc += __shfl_xor(zacc, 16);
    zacc += __shfl_xor(zacc, 32);
    if (l4 == 0 && grow < NG)
        pz[(bh * 4 + sl) * NG + grow] = zacc;

#pragma unroll
    for (int r = 0; r < 4; ++r) {
        int g = gt * 64 + wid * 16 + l4 * 4 + r;
        if (g < NG) {
            float* row = pN + ((size_t)(bh * 4 + sl) * NG + g) * 128;
#pragma unroll
            for (int n = 0; n < 8; ++n)
                row[n * 16 + l15] = acc[n][r];
        }
    }

    // ---- fused reduce: last of the 4 sl-blocks for (bh,gt) divides by z ----
    __threadfence();   // make pN/pz stores device-visible (release)
    if (tid == 0) oldc = atomicAdd(&cnt[bh * 4 + gt], 1u);
    __syncthreads();
    if (oldc == 3u) {
        __threadfence();   // acquire: other blocks' stores now visible
        const size_t slo = (size_t)NG * 128;
        int g = gt * 64 + (tid >> 2);
        if (g < NG) {
            float z = pz[(bh * 4 + 0) * NG + g] + pz[(bh * 4 + 1) * NG + g] +
                      pz[(bh * 4 + 2) * NG + g] + pz[(bh * 4 + 3) * NG + g];
            float zinv = 1.f / z;
            size_t r0 = ((size_t)(bh * 4) * NG + g) * 128;
            for (int v = (tid & 3); v < 32; v += 4) {
                float4 s0 = *(const float4*)&pN[r0 + v * 4];
                float4 s1 = *(const float4*)&pN[r0 + slo + v * 4];
                float4 s2 = *(const float4*)&pN[r0 + 2 * slo + v * 4];
                float4 s3 = *(const float4*)&pN[r0 + 3 * slo + v * 4];
                float4 o;
                o.x = (s0.x + s1.x + s2.x + s3.x) * zinv;
                o.y = (s0.y + s1.y + s2.y + s3.y) * zinv;
                o.z = (s0.z + s1.z + s2.z + s3.z) * zinv;
                o.w = (s0.w + s1.w + s2.w + s3.w) * zinv;
                *(float4*)&pN[r0 + v * 4] = o;   // tablef overlays slice 0
            }
        }
    }
}

// ---- k_eval: y = bo + sum_h Lagrange4(tablef[bh], p(a_bh,t)) ----  grid 512
// (R13-identical)
__global__ __launch_bounds__(256) void k_eval(const float* __restrict__ qs,
                                              const float* __restrict__ tablef,
                                              const float* __restrict__ mm,
                                              const float* __restrict__ bo,
                                              float* __restrict__ y) {
    int blk = blockIdx.x;
    int b = blk >> 7;
    int t = (blk & 127) * 16 + (threadIdx.x >> 4);
    int kk0 = (threadIdx.x & 15) * 8;

    float acc[8];
#pragma unroll
    for (int j = 0; j < 8; ++j) acc[j] = bo[kk0 + j];

#pragma unroll
    for (int h = 0; h < 8; ++h) {
        int bh = b * 8 + h;
        float a = qs[bh * 2048 + t] * A2SCALE;
        float amin = mm[bh * 2], hs = mm[bh * 2 + 1];
        float p = (a - amin) / hs;
        int g1 = (int)p;
        g1 = g1 < 1 ? 1 : (g1 > NG - 3 ? NG - 3 : g1);
        float u = p - (float)g1;
        float um1 = u - 1.f, um2 = u - 2.f, up1 = u + 1.f;
        float w0 = -u * um1 * um2 * (1.f / 6.f);
        float w1 = up1 * um1 * um2 * 0.5f;
        float w2 = -up1 * u * um2 * 0.5f;
        float w3 = up1 * u * um1 * (1.f / 6.f);
        const float* base = tablef + ((size_t)(bh * 4) * NG + (g1 - 1)) * 128 + kk0;
#pragma unroll
        for (int v = 0; v < 2; ++v) {
            float4 r0 = *(const float4*)(base + v * 4);
            float4 r1 = *(const float4*)(base + 128 + v * 4);
            float4 r2 = *(const float4*)(base + 256 + v * 4);
            float4 r3 = *(const float4*)(base + 384 + v * 4);
            acc[v * 4 + 0] += w0 * r0.x + w1 * r1.x + w2 * r2.x + w3 * r3.x;
            acc[v * 4 + 1] += w0 * r0.y + w1 * r1.y + w2 * r2.y + w3 * r3.y;
            acc[v * 4 + 2] += w0 * r0.z + w1 * r1.z + w2 * r2.z + w3 * r3.z;
            acc[v * 4 + 3] += w0 * r0.w + w1 * r1.w + w2 * r2.w + w3 * r3.w;
        }
    }
    float* yp = y + ((size_t)b * 2048 + t) * 128 + kk0;
    *(float4*)yp = make_float4(acc[0], acc[1], acc[2], acc[3]);
    *(float4*)(yp + 4) = make_float4(acc[4], acc[5], acc[6], acc[7]);
}

extern "C" void kernel_launch(void* const* d_in, const int* in_sizes, int n_in,
                              void* d_out, int out_size, void* d_ws, size_t ws_size,
                              hipStream_t stream) {
    const float* x  = (const float*)d_in[0];
    const float* Wq = (const float*)d_in[1];
    const float* Wk = (const float*)d_in[2];
    const float* Wv = (const float*)d_in[3];
    const float* Wo = (const float*)d_in[4];
    const float* bo = (const float*)d_in[5];
    float* y  = (float*)d_out;
    float* ws = (float*)d_ws;
    (void)in_sizes; (void)n_in; (void)out_size; (void)ws_size;

    unsigned short* u16 = (unsigned short*)(ws + OFF_U);
    unsigned* cnt = (unsigned*)(ws + OFF_CNT);
    float* pN = ws + OFF_PN;
    float* pz = y;             // scratch in d_out; overwritten by k_eval
    float* mm = ws + OFF_MM;   // dead-W2 region

    k_prep1<<<576, 256, 0, stream>>>(Wq, Wk, Wv, Wo, ws, ws + OFF_W2, cnt);
    k_prep2<<<768, 256, 0, stream>>>(x, ws, ws + OFF_W2, ws + OFF_QS, ws + OFF_KS, u16);
    k_table<<<512, 256, 0, stream>>>(ws + OFF_QS, ws + OFF_KS, u16, pN, pz, mm, cnt);
    k_eval<<<512, 256, 0, stream>>>(ws + OFF_QS, pN, mm, bo, y);
}

// Round 19
// 65.071 us; speedup vs baseline: 2.1379x; 2.1379x over previous
//
#include <hip/hip_runtime.h>
#include <math.h>

// Problem constants
#define NB 4
#define NC 2048
#define NH 8
#define NK 128
#define NG 255          // a-grid points per (b,h)

// exp2-domain logit scale: log2(e)/sqrt(128)
#define A2SCALE (1.4426950408889634f * 0.08838834764831845f)

typedef __attribute__((ext_vector_type(8))) short bf16x8;
typedef __attribute__((ext_vector_type(4))) float f32x4;

// ---------------- ws layout (float offsets) ----------------
// wspart [4][2048]           @ 0        (8192)
// W2     [8][128][128]       @ 8192     (131072)  dead after prep2 ->
//   mm   [32][2]             @ 8192     amin,hstep per bh (written k_table)
// qs     [32][2048]          @ 139264
// ks     [32][2048]          @ 204800
// u bf16 [32][64ig][8nt][64lane][8j] @ 270336 (8,388,608 ushort)
// partsN [32][4sl][255][128] @ 4464640  (4,177,920) -> slice0 becomes tablef
// parts_z [32][4][255] lives in d_out (overwritten by k_eval)
#define OFF_W2  8192
#define OFF_MM  8192
#define OFF_QS  139264
#define OFF_KS  204800
#define OFF_U   270336
#define OFF_PN  4464640

__device__ static inline float exp2_hw(float x) {
#if __has_builtin(__builtin_amdgcn_exp2f)
    return __builtin_amdgcn_exp2f(x);
#else
    float r;
    asm volatile("v_exp_f32 %0, %1\n\ts_nop 1" : "=v"(r) : "v"(x));
    return r;
#endif
}

__device__ static inline unsigned cvtpk(float lo, float hi) {
    unsigned r;
    asm("v_cvt_pk_bf16_f32 %0, %1, %2" : "=v"(r) : "v"(lo), "v"(hi));
    return r;
}

__device__ static inline bf16x8 pack8(float4 a, float4 b) {
    union { unsigned u[4]; bf16x8 v; } r;
    r.u[0] = cvtpk(a.x, a.y);
    r.u[1] = cvtpk(a.z, a.w);
    r.u[2] = cvtpk(b.x, b.y);
    r.u[3] = cvtpk(b.z, b.w);
    return r.v;
}

// 8 exps of (a*k + negM) packed to a bf16x8 A-fragment; accumulates sum in z
__device__ static inline bf16x8 pexp8s(float4 ka, float4 kb, float a, float negM,
                                       float& z) {
    float e0 = exp2_hw(fmaf(a, ka.x, negM));
    float e1 = exp2_hw(fmaf(a, ka.y, negM));
    float e2 = exp2_hw(fmaf(a, ka.z, negM));
    float e3 = exp2_hw(fmaf(a, ka.w, negM));
    float e4 = exp2_hw(fmaf(a, kb.x, negM));
    float e5 = exp2_hw(fmaf(a, kb.y, negM));
    float e6 = exp2_hw(fmaf(a, kb.z, negM));
    float e7 = exp2_hw(fmaf(a, kb.w, negM));
    z += ((e0 + e1) + (e2 + e3)) + ((e4 + e5) + (e6 + e7));
    union { unsigned u[4]; bf16x8 v; } r;
    r.u[0] = cvtpk(e0, e1);
    r.u[1] = cvtpk(e2, e3);
    r.u[2] = cvtpk(e4, e5);
    r.u[3] = cvtpk(e6, e7);
    return r.v;
}

// ---- prep1: (blk<64) wsum ; (blk>=64) W2 ----  grid 576 x 256
__global__ __launch_bounds__(256) void k_prep1(const float* __restrict__ Wq,
                                               const float* __restrict__ Wk,
                                               const float* __restrict__ Wv,
                                               const float* __restrict__ Wo,
                                               float* __restrict__ wspart,
                                               float* __restrict__ W2) {
    int blk = blockIdx.x;
    int tid = threadIdx.x;
    __shared__ float sh[256];
    if (blk < 64) {
        int which = blk >> 5, h = (blk >> 2) & 7, eq = blk & 3;
        const float* W = which ? Wk : Wq;
        int m = tid & 127, part = tid >> 7;
        const float* base = W + (h * 128 + eq * 32 + part * 16) * 128 + m;
        float s = 0.f;
#pragma unroll
        for (int e = 0; e < 16; ++e) s += base[e * 128];
        if (part) sh[m] = s;
        __syncthreads();
        if (!part) wspart[eq * 2048 + which * 1024 + h * 128 + m] = s + sh[m];
    } else {
        int idx = blk - 64;                    // 0..511
        int h = idx >> 6;
        int kl = tid >> 7;                     // 0..1
        int kk = (idx & 63) * 2 + kl;
        int m = tid & 127;
        float* wo_s = sh;                      // [2][128]
        wo_s[kl * 128 + m] = Wo[kk * 1024 + h * 128 + m];
        __syncthreads();
        const float* base = Wv + (h * 128) * 128 + m;
        const float* wrow = &wo_s[kl * 128];
        float s = 0.f;
#pragma unroll 4
        for (int e = 0; e < 128; ++e) s += base[e * 128] * wrow[e];
        W2[(h * 128 + kk) * 128 + m] = s;
    }
}

// ---- prep2: (blk<256) qs/ks ; (blk>=256) u-GEMM ----  grid 768 x 256
__global__ __launch_bounds__(256) void k_prep2(const float* __restrict__ x,
                                               const float* __restrict__ wspart,
                                               const float* __restrict__ W2,
                                               float* __restrict__ qs,
                                               float* __restrict__ ks,
                                               unsigned short* __restrict__ u16) {
    __shared__ __align__(16) unsigned char smem_u8[32768];
    int tid = threadIdx.x;
    int blk = blockIdx.x;
    if (blk < 256) {
        float* xs = (float*)smem_u8;              // [32][129]
        float* wsum = (float*)smem_u8 + 32 * 129; // [2048]
        for (int j = tid; j < 2048; j += 256)
            wsum[j] = wspart[j] + wspart[2048 + j] + wspart[4096 + j] + wspart[6144 + j];
        int row0 = blk * 32;
        for (int j = tid; j < 32 * 128; j += 256) {
            int r = j >> 7, m = j & 127;
            xs[r * 129 + m] = x[(size_t)(row0 + r) * 128 + m];
        }
        __syncthreads();
#pragma unroll
        for (int jj = 0; jj < 2; ++jj) {
            int o = tid + 256 * jj;
            int r = o & 31;
            int q = o >> 5;
            int which = q >> 3, h = q & 7;
            const float* wrow = &wsum[which * 1024 + h * 128];
            const float* xrow = &xs[r * 129];
            float s = 0.f;
#pragma unroll 4
            for (int m = 0; m < 128; ++m) s += xrow[m] * wrow[m];
            int row = row0 + r, b = row >> 11, t = row & 2047;
            float* dst = which ? ks : qs;
            dst[(b * 8 + h) * 2048 + t] = s;
        }
    } else {
        int gid = blk - 256;
        int xcd = gid & 7, s = gid >> 3;
        int bh = xcd * 4 + (s >> 4);
        int it = s & 15;
        int b = bh >> 3, h = bh & 7;
        int lane = tid & 63, wid = tid >> 6;
        int wr = wid >> 1, wc = wid & 1;
        int l15 = lane & 15, l4 = lane >> 4;

        const float* xb = x + (size_t)(b * 2048 + it * 128) * 128;
        const float* w2h = W2 + h * 16384;

        f32x4 acc[4][4];
#pragma unroll
        for (int m = 0; m < 4; ++m)
#pragma unroll
            for (int n = 0; n < 4; ++n) acc[m][n] = (f32x4)0.f;

#pragma unroll
        for (int mg = 0; mg < 4; ++mg) {
            bf16x8 af[4], bfr[4];
#pragma unroll
            for (int m = 0; m < 4; ++m) {
                const float* src = xb + (wr * 64 + m * 16 + l15) * 128 + mg * 32 + l4 * 8;
                af[m] = pack8(*(const float4*)src, *(const float4*)(src + 4));
            }
#pragma unroll
            for (int n = 0; n < 4; ++n) {
                const float* src = w2h + (wc * 64 + n * 16 + l15) * 128 + mg * 32 + l4 * 8;
                bfr[n] = pack8(*(const float4*)src, *(const float4*)(src + 4));
            }
#pragma unroll
            for (int m = 0; m < 4; ++m)
#pragma unroll
                for (int n = 0; n < 4; ++n)
                    acc[m][n] = __builtin_amdgcn_mfma_f32_16x16x32_bf16(
                        af[m], bfr[n], acc[m][n], 0, 0, 0);
        }

        unsigned* u_sh = (unsigned*)smem_u8;
#pragma unroll
        for (int m = 0; m < 4; ++m) {
            int i_base = wr * 64 + m * 16 + l4 * 4;
            int ig = i_base >> 5;
            int lg = 16 * ((i_base >> 3) & 3);
            int jp = (i_base & 7) >> 1;
#pragma unroll
            for (int n = 0; n < 4; ++n) {
                int kk = wc * 64 + n * 16 + l15;
                int lp = (kk & 15) + lg;
                int idx = ((ig * 8 + (kk >> 4)) * 64 + lp) * 4 + jp;
                uint2 w;
                w.x = cvtpk(acc[m][n][0], acc[m][n][1]);
                w.y = cvtpk(acc[m][n][2], acc[m][n][3]);
                *(uint2*)&u_sh[idx] = w;
            }
        }
        __syncthreads();
        unsigned short* ub = u16 + ((size_t)(b * 8 + h) * 64 + it * 4) * 4096;
#pragma unroll
        for (int q = 0; q < 8; ++q)
            ((uint4*)ub)[tid + q * 256] = ((const uint4*)u_sh)[tid + q * 256];
    }
}

// ---- k_table: tabulate N_g, z_g on the a-grid, per (bh, 64-g tile, i-slice) ----
// grid 512 x 256: 32 bh x 4 gtiles x 4 islices(512 i).
__global__ __launch_bounds__(256, 2) void k_table(const float* __restrict__ qs,
                                                  const float* __restrict__ ks,
                                                  const unsigned short* __restrict__ ub,
                                                  float* __restrict__ pN,
                                                  float* __restrict__ pz,
                                                  float* __restrict__ mm) {
    int L = blockIdx.x;
    int xcd = L & 7, s = L >> 3;
    int bh = xcd * 4 + (s >> 4);
    int rem = s & 15;
    int gt = rem >> 2, sl = rem & 3;
    int tid = threadIdx.x;
    int lane = tid & 63, wid = tid >> 6;
    int l15 = lane & 15, l4 = lane >> 4;

    __shared__ float kss[2048];
    __shared__ __align__(16) unsigned short u_l[3][4096];
    __shared__ float red[8];

    // ---- phase 1: qs min/max -> amin, hstep ----
    for (int j = tid; j < 512; j += 256)
        ((float4*)kss)[j] = ((const float4*)(qs + bh * 2048))[j];
    __syncthreads();
    float mn = 1e30f, mx = -1e30f;
    {
        const float4* ka = (const float4*)kss;
#pragma unroll
        for (int jj = 0; jj < 2; ++jj) {
            float4 v = ka[tid + jj * 256];
            mn = fminf(mn, fminf(fminf(v.x, v.y), fminf(v.z, v.w)));
            mx = fmaxf(mx, fmaxf(fmaxf(v.x, v.y), fmaxf(v.z, v.w)));
        }
#pragma unroll
        for (int off = 32; off; off >>= 1) {
            mn = fminf(mn, __shfl_xor(mn, off));
            mx = fmaxf(mx, __shfl_xor(mx, off));
        }
        if (!lane) { red[wid] = mn; red[4 + wid] = mx; }
    }
    __syncthreads();
    mn = fminf(fminf(red[0], red[1]), fminf(red[2], red[3]));
    mx = fmaxf(fmaxf(red[4], red[5]), fmaxf(red[6], red[7]));
    float amin = mn * A2SCALE;
    float hstep = fmaxf((mx * A2SCALE - amin), 1e-6f) * (1.f / (NG - 1));
    if (tid == 0) { mm[bh * 2] = amin; mm[bh * 2 + 1] = hstep; }  // identical dup writes
    __syncthreads();

    // ---- phase 2: ks stage + global min/max ----
    for (int j = tid; j < 512; j += 256)
        ((float4*)kss)[j] = ((const float4*)(ks + bh * 2048))[j];
    __syncthreads();
    mn = 1e30f; mx = -1e30f;
    {
        const float4* ka = (const float4*)kss;
#pragma unroll
        for (int jj = 0; jj < 2; ++jj) {
            float4 v = ka[tid + jj * 256];
            mn = fminf(mn, fminf(fminf(v.x, v.y), fminf(v.z, v.w)));
            mx = fmaxf(mx, fmaxf(fmaxf(v.x, v.y), fmaxf(v.z, v.w)));
        }
#pragma unroll
        for (int off = 32; off; off >>= 1) {
            mn = fminf(mn, __shfl_xor(mn, off));
            mx = fmaxf(mx, __shfl_xor(mx, off));
        }
        if (!lane) { red[wid] = mn; red[4 + wid] = mx; }
    }
    __syncthreads();
    mn = fminf(fminf(red[0], red[1]), fminf(red[2], red[3]));
    mx = fmaxf(fmaxf(red[4], red[5]), fmaxf(red[6], red[7]));

    // grid-row a value (rows of this wave: gt*64 + wid*16 + l15)
    int grow = gt * 64 + wid * 16 + l15;
    float a = fmaf((float)grow, hstep, amin);
    float negM = -(a > 0.f ? a * mx : a * mn);   // exact max over ALL i (consistent across slices)
    float zacc = 0.f;

    const unsigned short* gub = ub + (size_t)bh * 262144 + (size_t)sl * 65536;

    f32x4 acc[8];
#pragma unroll
    for (int n = 0; n < 8; ++n) acc[n] = (f32x4)0.f;

#define DMA(cnv, buf) do {                                                     \
    const unsigned short* src_ = gub + (size_t)(cnv) * 4096;                   \
    _Pragma("unroll")                                                          \
    for (int q_ = 0; q_ < 2; ++q_) {                                           \
        int seg_ = q_ * 4 + wid;                                               \
        __builtin_amdgcn_global_load_lds(                                      \
            (const __attribute__((address_space(1))) unsigned int*)(src_ + seg_ * 512 + lane * 8), \
            (__attribute__((address_space(3))) unsigned int*)(&u_l[buf][seg_ * 512]),              \
            16, 0, 0);                                                         \
    }                                                                          \
} while (0)

    DMA(0, 0);
    DMA(1, 1);
    for (int cn = 0; cn < 15; ++cn) {
        int cur = cn % 3;
        int ib = sl * 512 + cn * 32;
        float4 ka = *(const float4*)&kss[ib + l4 * 8];
        float4 kb = *(const float4*)&kss[ib + l4 * 8 + 4];
        bf16x8 pf = pexp8s(ka, kb, a, negM, zacc);

        // wait: chunk cn landed (chunk cn+1's 2 insts stay in flight)
        asm volatile("s_waitcnt vmcnt(2)" ::: "memory");
        __builtin_amdgcn_sched_barrier(0);
        __builtin_amdgcn_s_barrier();
        __builtin_amdgcn_sched_barrier(0);
        if (cn + 2 <= 15) DMA(cn + 2, (cn + 2) % 3);
        __builtin_amdgcn_sched_barrier(0);

        __builtin_amdgcn_s_setprio(1);
#pragma unroll
        for (int n = 0; n < 8; ++n) {
            bf16x8 uf = *(const bf16x8*)&u_l[cur][n * 512 + lane * 8];
            acc[n] = __builtin_amdgcn_mfma_f32_16x16x32_bf16(pf, uf, acc[n], 0, 0, 0);
        }
        __builtin_amdgcn_s_setprio(0);
    }
    {   // tail: chunk 15 (buf 15%3 == 0)
        int ib = sl * 512 + 15 * 32;
        float4 ka = *(const float4*)&kss[ib + l4 * 8];
        float4 kb = *(const float4*)&kss[ib + l4 * 8 + 4];
        bf16x8 pf = pexp8s(ka, kb, a, negM, zacc);
        asm volatile("s_waitcnt vmcnt(0)" ::: "memory");
        __builtin_amdgcn_sched_barrier(0);
        __builtin_amdgcn_s_barrier();
        __builtin_amdgcn_sched_barrier(0);
#pragma unroll
        for (int n = 0; n < 8; ++n) {
            bf16x8 uf = *(const bf16x8*)&u_l[0][n * 512 + lane * 8];
            acc[n] = __builtin_amdgcn_mfma_f32_16x16x32_bf16(pf, uf, acc[n], 0, 0, 0);
        }
    }
#undef DMA

    // z: reduce over l4 groups -> lanes sharing l15 hold row-z
    zacc += __shfl_xor(zacc, 16);
    zacc += __shfl_xor(zacc, 32);
    if (l4 == 0 && grow < NG)
        pz[(bh * 4 + sl) * NG + grow] = zacc;

    // N: C/D layout col=lane&15, row=(lane>>4)*4+reg. Plain stores (exclusive).
#pragma unroll
    for (int r = 0; r < 4; ++r) {
        int g = gt * 64 + wid * 16 + l4 * 4 + r;
        if (g < NG) {
            float* row = pN + ((size_t)(bh * 4 + sl) * NG + g) * 128;
#pragma unroll
            for (int n = 0; n < 8; ++n)
                row[n * 16 + l15] = acc[n][r];
        }
    }
}

// ---- k_reduce: tablef[bh][g][kk] = sum_sl N / sum_sl z  (in-place over slice 0) ----
// grid 256 x 256: blk -> (bh, 32-g group)
__global__ __launch_bounds__(256) void k_reduce(float* __restrict__ pN,
                                                const float* __restrict__ pz) {
    int blk = blockIdx.x;
    int bh = blk >> 3;
    int g = (blk & 7) * 32 + (threadIdx.x >> 3);
    if (g >= NG) return;
    int kq = (threadIdx.x & 7) * 16;   // 16 kk per thread
    float z = pz[(bh * 4 + 0) * NG + g] + pz[(bh * 4 + 1) * NG + g] +
              pz[(bh * 4 + 2) * NG + g] + pz[(bh * 4 + 3) * NG + g];
    float zinv = 1.f / z;
    size_t r0 = ((size_t)(bh * 4 + 0) * NG + g) * 128 + kq;
    size_t r1 = ((size_t)(bh * 4 + 1) * NG + g) * 128 + kq;
    size_t r2 = ((size_t)(bh * 4 + 2) * NG + g) * 128 + kq;
    size_t r3 = ((size_t)(bh * 4 + 3) * NG + g) * 128 + kq;
#pragma unroll
    for (int v = 0; v < 4; ++v) {
        float4 s0 = *(const float4*)&pN[r0 + v * 4];
        float4 s1 = *(const float4*)&pN[r1 + v * 4];
        float4 s2 = *(const float4*)&pN[r2 + v * 4];
        float4 s3 = *(const float4*)&pN[r3 + v * 4];
        float4 o;
        o.x = (s0.x + s1.x + s2.x + s3.x) * zinv;
        o.y = (s0.y + s1.y + s2.y + s3.y) * zinv;
        o.z = (s0.z + s1.z + s2.z + s3.z) * zinv;
        o.w = (s0.w + s1.w + s2.w + s3.w) * zinv;
        *(float4*)&pN[r0 + v * 4] = o;   // tablef overlays slice 0
    }
}

// ---- k_eval: y[b][t][kk] = bo[kk] + sum_h Lagrange4(tablef[bh], p(a_bh,t)) ----
// grid 512 x 256: blk -> (b, 16-row tile); thread -> (row, 8-kk group)
__global__ __launch_bounds__(256) void k_eval(const float* __restrict__ qs,
                                              const float* __restrict__ tablef,
                                              const float* __restrict__ mm,
                                              const float* __restrict__ bo,
                                              float* __restrict__ y) {
    int blk = blockIdx.x;
    int b = blk >> 7;
    int t = (blk & 127) * 16 + (threadIdx.x >> 4);
    int kk0 = (threadIdx.x & 15) * 8;

    float acc[8];
#pragma unroll
    for (int j = 0; j < 8; ++j) acc[j] = bo[kk0 + j];

#pragma unroll
    for (int h = 0; h < 8; ++h) {
        int bh = b * 8 + h;
        float a = qs[bh * 2048 + t] * A2SCALE;
        float amin = mm[bh * 2], hs = mm[bh * 2 + 1];
        float p = (a - amin) / hs;
        int g1 = (int)p;
        g1 = g1 < 1 ? 1 : (g1 > NG - 3 ? NG - 3 : g1);
        float u = p - (float)g1;
        // 4-point Lagrange weights on nodes {-1,0,1,2}
        float um1 = u - 1.f, um2 = u - 2.f, up1 = u + 1.f;
        float w0 = -u * um1 * um2 * (1.f / 6.f);
        float w1 = up1 * um1 * um2 * 0.5f;
        float w2 = -up1 * u * um2 * 0.5f;
        float w3 = up1 * u * um1 * (1.f / 6.f);
        const float* base = tablef + ((size_t)(bh * 4) * NG + (g1 - 1)) * 128 + kk0;
#pragma unroll
        for (int v = 0; v < 2; ++v) {
            float4 r0 = *(const float4*)(base + v * 4);
            float4 r1 = *(const float4*)(base + 128 + v * 4);
            float4 r2 = *(const float4*)(base + 256 + v * 4);
            float4 r3 = *(const float4*)(base + 384 + v * 4);
            acc[v * 4 + 0] += w0 * r0.x + w1 * r1.x + w2 * r2.x + w3 * r3.x;
            acc[v * 4 + 1] += w0 * r0.y + w1 * r1.y + w2 * r2.y + w3 * r3.y;
            acc[v * 4 + 2] += w0 * r0.z + w1 * r1.z + w2 * r2.z + w3 * r3.z;
            acc[v * 4 + 3] += w0 * r0.w + w1 * r1.w + w2 * r2.w + w3 * r3.w;
        }
    }
    float* yp = y + ((size_t)b * 2048 + t) * 128 + kk0;
    *(float4*)yp = make_float4(acc[0], acc[1], acc[2], acc[3]);
    *(float4*)(yp + 4) = make_float4(acc[4], acc[5], acc[6], acc[7]);
}

extern "C" void kernel_launch(void* const* d_in, const int* in_sizes, int n_in,
                              void* d_out, int out_size, void* d_ws, size_t ws_size,
                              hipStream_t stream) {
    const float* x  = (const float*)d_in[0];
    const float* Wq = (const float*)d_in[1];
    const float* Wk = (const float*)d_in[2];
    const float* Wv = (const float*)d_in[3];
    const float* Wo = (const float*)d_in[4];
    const float* bo = (const float*)d_in[5];
    float* y  = (float*)d_out;
    float* ws = (float*)d_ws;
    (void)in_sizes; (void)n_in; (void)out_size; (void)ws_size;

    unsigned short* u16 = (unsigned short*)(ws + OFF_U);
    float* pN = ws + OFF_PN;
    float* pz = y;             // scratch in d_out; overwritten by k_eval
    float* mm = ws + OFF_MM;   // dead-W2 region

    k_prep1<<<576, 256, 0, stream>>>(Wq, Wk, Wv, Wo, ws, ws + OFF_W2);
    k_prep2<<<768, 256, 0, stream>>>(x, ws, ws + OFF_W2, ws + OFF_QS, ws + OFF_KS, u16);
    k_table<<<512, 256, 0, stream>>>(ws + OFF_QS, ws + OFF_KS, u16, pN, pz, ws + OFF_MM);
    k_reduce<<<256, 256, 0, stream>>>(pN, pz);
    k_eval<<<512, 256, 0, stream>>>(ws + OFF_QS, pN, ws + OFF_MM, bo, y);
}